// Round 22
// baseline (1324.266 us; speedup 1.0000x reference)
//
#include <hip/hip_runtime.h>
#include <math.h>

// ---------------------------------------------------------------------------
// B=2, S=2048, QW=1024, H=16, M=4096, D=64, K=32, OW=1024
// Split-bf16 MFMA scores + bitonic init + serial merge; keys in REGISTERS
// (r21) with r22 fix (ONE change): restore T14 ordering — B(next) loads
// issue BEFORE the merge, MFMA runs AFTER it, so L2 latency hides under the
// merge's ~2K-cycle VALU/crossbar chain (r21 had MFMA right after the loads
// -> every chunk stalled on L2; 832->901 regression vs r19).
// Loop: load_B(next) -> cand ds_reads -> merge -> barrier -> mfma -> barrier.
// Numerics identical to r6-r21 (absmax 0.171875).
// ---------------------------------------------------------------------------

#define EPS1f 6e-5f
#define EPS2f 2e-4f

typedef __attribute__((ext_vector_type(8))) short bf16x8;
typedef __attribute__((ext_vector_type(4))) float f32x4;

__device__ __forceinline__ ushort f2bf(float f) {      // RNE float->bf16
    uint u = __float_as_uint(f);
    u += 0x7FFFu + ((u >> 16) & 1u);
    return (ushort)(u >> 16);
}
__device__ __forceinline__ float bf2f(ushort h) {
    return __uint_as_float(((uint)h) << 16);
}

// ascending stable bitonic stage: smaller val first; tie -> larger idx first
__device__ __forceinline__ void bstageA(float& v, int& i, int lane, int j, int k) {
    float pv = __shfl_xor(v, j);
    int   pi = __shfl_xor(i, j);
    bool want_small = (((lane & k) == 0) == ((lane & j) == 0));
    bool me_small   = (v < pv) || (v == pv && i > pi);
    if (want_small != me_small) { v = pv; i = pi; }
}

// ---- keys: kH/kL[h][m][e] = bf16split(sum_d memory[h][m][d]*Wk[h][d][e]+bk)
__global__ __launch_bounds__(256) void keys_kernel(
    const float* __restrict__ mem, const float* __restrict__ Wk,
    const float* __restrict__ bk, ushort* __restrict__ kH,
    ushort* __restrict__ kL)
{
    int o = blockIdx.x * 256 + threadIdx.x;   // h*2^18 + m*64 + e
    int e = o & 63;
    int m = (o >> 6) & 4095;
    int h = o >> 18;
    const float* mrow = mem + (size_t)((h << 12) + m) * 64;
    const float* wcol = Wk + (h << 12) + e;   // stride 64 over d
    double acc = (double)bk[(h << 6) + e];
    #pragma unroll
    for (int d = 0; d < 64; ++d) acc += (double)mrow[d] * (double)wcol[d << 6];
    float v = (float)acc;
    ushort hi = f2bf(v);
    kH[o] = hi;
    kL[o] = f2bf(v - bf2f(hi));
}

// ---- q-proj: fp32 128x128x16 GEMM, epilogue emits bf16 hi/lo planes -------
__global__ __launch_bounds__(256) void gemm_bias_bf16out_kernel(
    const float* __restrict__ A, const float* __restrict__ B,
    const float* __restrict__ bias, ushort* __restrict__ qH,
    ushort* __restrict__ qL, int M, int N, int K)
{
    __shared__ float AsT[16][132];
    __shared__ float Bs[16][132];
    int t  = threadIdx.x;
    int m0 = blockIdx.y * 128, n0 = blockIdx.x * 128;
    int tm = t >> 4, tn = t & 15;
    float acc[8][8] = {};
    for (int k0 = 0; k0 < K; k0 += 16) {
        __syncthreads();
        #pragma unroll
        for (int j = 0; j < 8; ++j) {
            int i = t + j * 256;
            int r = i >> 4, c = i & 15;
            AsT[c][r] = A[(size_t)(m0 + r) * K + k0 + c];
        }
        #pragma unroll
        for (int j = 0; j < 8; ++j) {
            int i = t + j * 256;
            int kk = i >> 7, nn = i & 127;
            Bs[kk][nn] = B[(size_t)(k0 + kk) * N + n0 + nn];
        }
        __syncthreads();
        #pragma unroll
        for (int kk = 0; kk < 16; ++kk) {
            float a[8], b[8];
            *(float4*)&a[0] = *(const float4*)&AsT[kk][tm * 8];
            *(float4*)&a[4] = *(const float4*)&AsT[kk][tm * 8 + 4];
            *(float4*)&b[0] = *(const float4*)&Bs[kk][tn * 8];
            *(float4*)&b[4] = *(const float4*)&Bs[kk][tn * 8 + 4];
            #pragma unroll
            for (int i = 0; i < 8; ++i)
                #pragma unroll
                for (int j = 0; j < 8; ++j)
                    acc[i][j] += a[i] * b[j];
        }
    }
    float bv[8];
    *(float4*)&bv[0] = *(const float4*)&bias[n0 + tn * 8];
    *(float4*)&bv[4] = *(const float4*)&bias[n0 + tn * 8 + 4];
    #pragma unroll
    for (int i = 0; i < 8; ++i) {
        uint ph[4], pl[4];
        #pragma unroll
        for (int j = 0; j < 4; ++j) {
            float o0 = acc[i][2 * j]     + bv[2 * j];
            float o1 = acc[i][2 * j + 1] + bv[2 * j + 1];
            ushort h0 = f2bf(o0), h1 = f2bf(o1);
            ushort l0 = f2bf(o0 - bf2f(h0)), l1 = f2bf(o1 - bf2f(h1));
            ph[j] = (uint)h0 | ((uint)h1 << 16);
            pl[j] = (uint)l0 | ((uint)l1 << 16);
        }
        size_t off = (size_t)(m0 + tm * 8 + i) * N + n0 + tn * 8;
        *(uint4*)&qH[off] = make_uint4(ph[0], ph[1], ph[2], ph[3]);
        *(uint4*)&qL[off] = make_uint4(pl[0], pl[1], pl[2], pl[3]);
    }
}

// ---- fused MFMA score + top-35 (bitonic init + serial merge) + blend ------
// Block 256 (4 waves), one (b,h), 32 s-rows, 64 m-chunks of 64.
// MFMA: wave w computes row-tile (w>>1), col-tiles {(w&1)*2, +1}; B-operands
// loaded straight from global (L2) into registers each chunk — NO key LDS.
// Merge: wave w owns rows w*8..w*8+7; list ascending on lanes 0..34.
__global__ __launch_bounds__(256) void score_topk_blend_kernel(
    const ushort* __restrict__ qHg, const ushort* __restrict__ qLg,
    const ushort* __restrict__ kHg, const ushort* __restrict__ kLg,
    const float* __restrict__ mem, float* __restrict__ att)
{
    __shared__ float sc_s[32 * 68];   // 8704 B scores
    __shared__ float gf_s[32 * 36];   // 4608 B gates
    __shared__ int   gi_s[32 * 36];   // 4608 B indices

    int t     = threadIdx.x;
    int stile = blockIdx.x;          // 0..63
    int h     = blockIdx.y;
    int b     = blockIdx.z;
    int bs0   = b * 2048 + stile * 32;
    int lane  = t & 63;
    int w     = t >> 6;

    int fr  = lane & 15;             // fragment row/col
    int fk  = (lane >> 4) * 8;       // fragment k base
    int rt  = w >> 1;                // compute row-tile
    int ct0 = (w & 1) * 2;           // first compute col-tile

    // ---- q fragments directly from global, ONCE (resident in 16 VGPRs) ----
    bf16x8 Ah[2], Al[2];
    {
        size_t qoff = ((size_t)(bs0 + rt * 16 + fr) << 10) + (h << 6);
        const ushort* qh = qHg + qoff;
        const ushort* ql = qLg + qoff;
        #pragma unroll
        for (int k2 = 0; k2 < 2; ++k2) {
            Ah[k2] = *(const bf16x8*)&qh[k2 * 32 + fk];
            Al[k2] = *(const bf16x8*)&ql[k2 * 32 + fk];
        }
    }

    float LV[8]; int LI[8];
    #pragma unroll
    for (int r = 0; r < 8; ++r) {
        LV[r] = (lane < 35) ? -INFINITY : INFINITY;
        LI[r] = 0;
    }
    int rowbase = w * 8;

    const ushort* kHh = kHg + ((size_t)h << 18);
    const ushort* kLh = kLg + ((size_t)h << 18);

    // B-fragments for chunk m0 straight from global (L2): tiles ct0, ct0+1
    bf16x8 Bh[2][2], Bl[2][2];
    auto load_B = [&](int m0) {
        #pragma unroll
        for (int j = 0; j < 2; ++j) {
            size_t koff = ((size_t)(m0 + (ct0 + j) * 16 + fr) << 6);
            const ushort* ph = kHh + koff;
            const ushort* pl = kLh + koff;
            #pragma unroll
            for (int k2 = 0; k2 < 2; ++k2) {
                Bh[j][k2] = *(const bf16x8*)&ph[k2 * 32 + fk];
                Bl[j][k2] = *(const bf16x8*)&pl[k2 * 32 + fk];
            }
        }
    };

    auto do_mfma = [&]() {
        #pragma unroll
        for (int j = 0; j < 2; ++j) {
            f32x4 a = {0.f, 0.f, 0.f, 0.f};
            #pragma unroll
            for (int k2 = 0; k2 < 2; ++k2) {
                a = __builtin_amdgcn_mfma_f32_16x16x32_bf16(Ah[k2], Bh[j][k2], a, 0, 0, 0);
                a = __builtin_amdgcn_mfma_f32_16x16x32_bf16(Ah[k2], Bl[j][k2], a, 0, 0, 0);
                a = __builtin_amdgcn_mfma_f32_16x16x32_bf16(Al[k2], Bh[j][k2], a, 0, 0, 0);
                a = __builtin_amdgcn_mfma_f32_16x16x32_bf16(Al[k2], Bl[j][k2], a, 0, 0, 0);
            }
            int col = (ct0 + j) * 16 + fr;
            int rb  = rt * 16 + (lane >> 4) * 4;
            #pragma unroll
            for (int r = 0; r < 4; ++r)
                sc_s[(rb + r) * 68 + col] = a[r];
        }
    };

    // streaming serial merge of one chunk (r8-validated), cands in regs
    auto do_merge = [&](int m0, float* cand) {
        #pragma unroll
        for (int ri = 0; ri < 8; ++ri) {
            float c = cand[ri];
            float THR = __shfl(LV[ri], 0);
            while (true) {
                unsigned long long mb = __ballot(c > THR);
                if (mb == 0) break;
                int cc = __ffsll(mb) - 1;
                float val = __shfl(c, cc);
                if (lane == cc) c = -INFINITY;
                unsigned long long less = __ballot(LV[ri] < val);
                int p = __popcll(less);
                float nv = __shfl(LV[ri], lane + 1);
                int   ni = __shfl(LI[ri], lane + 1);
                if (lane == p - 1)      { LV[ri] = val; LI[ri] = m0 + cc; }
                else if (lane < p - 1)  { LV[ri] = nv;  LI[ri] = ni;  }
                THR = __shfl(LV[ri], 0);
            }
        }
    };

    // ---- prologue: B(0) -> MFMA -> sc(0) ----
    load_B(0);
    do_mfma();
    __syncthreads();                 // sc(0) visible

    // ---- pipelined loop: loads(next) -> cand -> merge -> mfma ----
    for (int chunk = 0; chunk < 63; ++chunk) {
        int m0 = chunk << 6;
        load_B(m0 + 64);             // issue next chunk's key loads (L2)

        float cand[8];
        #pragma unroll
        for (int ri = 0; ri < 8; ++ri)
            cand[ri] = sc_s[(rowbase + ri) * 68 + lane];

        if (chunk == 0) {
            // bitonic init: sort 64 candidates, keep top-35 (stable order)
            #pragma unroll
            for (int ri = 0; ri < 8; ++ri) {
                float v = cand[ri];
                int   i = lane;                       // m0 == 0
                #pragma unroll
                for (int k = 2; k <= 64; k <<= 1)
                    #pragma unroll
                    for (int j2 = k >> 1; j2 > 0; j2 >>= 1)
                        bstageA(v, i, lane, j2, k);
                int src = (lane < 35) ? lane + 29 : 0;
                float sv = __shfl(v, src);
                int   si = __shfl(i, src);
                LV[ri] = (lane < 35) ? sv : INFINITY;
                LI[ri] = (lane < 35) ? si : 0;
            }
        } else {
            do_merge(m0, cand);      // L2 latency of load_B hides here
        }

        __syncthreads();             // all cand reads done; sc free
        do_mfma();                   // B(next) landed; writes sc(chunk+1)
        __syncthreads();             // sc(chunk+1) visible
    }

    {   // final chunk 63
        float cand[8];
        #pragma unroll
        for (int ri = 0; ri < 8; ++ri)
            cand[ri] = sc_s[(rowbase + ri) * 68 + lane];
        do_merge(63 << 6, cand);
    }

    // blend masses + gates (lane l<35 holds rank 35-l; lane 34 = rank 1)
    #pragma unroll
    for (int ri = 0; ri < 8; ++ri) {
        int row = rowbase + ri;
        float v35 = __shfl(LV[ri], 0);
        float v34 = __shfl(LV[ri], 1);
        float v33 = __shfl(LV[ri], 2);
        float s32 = __shfl(LV[ri], 3);
        auto ramp = [](float gap) -> float {
            if (gap <= EPS1f) return 1.f;
            if (gap >= EPS2f) return 0.f;
            return (EPS2f - gap) / (EPS2f - EPS1f);
        };
        float u33 = ramp(s32 - v33), u34 = ramp(s32 - v34), u35 = ramp(s32 - v35);
        float inv = 1.f / (1.f + u33 + u34 + u35);
        float mass = (lane >= 4) ? 1.f
                   : (lane == 3) ? inv
                   : (lane == 2) ? u33 * inv
                   : (lane == 1) ? u34 * inv
                                 : u35 * inv;
        if (lane < 35) {
            gf_s[row * 36 + lane] = mass / (1.f + expf(-LV[ri]));
            gi_s[row * 36 + lane] = LI[ri];
        }
    }
    __syncthreads();

    // gather: wave w rows w*8..+7, lane = d
    for (int ri = 0; ri < 8; ++ri) {
        int row = rowbase + ri;
        float acc = 0.f;
        #pragma unroll 7
        for (int j = 0; j < 35; ++j) {
            float g  = gf_s[row * 36 + j];
            int  idx = gi_s[row * 36 + j];
            acc += g * mem[((size_t)((h << 12) + idx) << 6) + lane];
        }
        att[(size_t)(bs0 + row) * 1024 + (h << 6) + lane] = acc;
    }
}

// ---- out-proj: fp32 GEMM + bias -------------------------------------------
__global__ __launch_bounds__(256) void gemm_bias_kernel(
    const float* __restrict__ A, const float* __restrict__ B,
    const float* __restrict__ bias, float* __restrict__ C,
    int M, int N, int K)
{
    __shared__ float AsT[16][132];
    __shared__ float Bs[16][132];
    int t  = threadIdx.x;
    int m0 = blockIdx.y * 128, n0 = blockIdx.x * 128;
    int tm = t >> 4, tn = t & 15;
    float acc[8][8] = {};
    for (int k0 = 0; k0 < K; k0 += 16) {
        __syncthreads();
        #pragma unroll
        for (int j = 0; j < 8; ++j) {
            int i = t + j * 256;
            int r = i >> 4, c = i & 15;
            AsT[c][r] = A[(size_t)(m0 + r) * K + k0 + c];
        }
        #pragma unroll
        for (int j = 0; j < 8; ++j) {
            int i = t + j * 256;
            int kk = i >> 7, nn = i & 127;
            Bs[kk][nn] = B[(size_t)(k0 + kk) * N + n0 + nn];
        }
        __syncthreads();
        #pragma unroll
        for (int kk = 0; kk < 16; ++kk) {
            float a[8], b[8];
            *(float4*)&a[0] = *(const float4*)&AsT[kk][tm * 8];
            *(float4*)&a[4] = *(const float4*)&AsT[kk][tm * 8 + 4];
            *(float4*)&b[0] = *(const float4*)&Bs[kk][tn * 8];
            *(float4*)&b[4] = *(const float4*)&Bs[kk][tn * 8 + 4];
            #pragma unroll
            for (int i = 0; i < 8; ++i)
                #pragma unroll
                for (int j = 0; j < 8; ++j)
                    acc[i][j] += a[i] * b[j];
        }
    }
    float bv[8];
    *(float4*)&bv[0] = *(const float4*)&bias[n0 + tn * 8];
    *(float4*)&bv[4] = *(const float4*)&bias[n0 + tn * 8 + 4];
    #pragma unroll
    for (int i = 0; i < 8; ++i) {
        float o8[8];
        #pragma unroll
        for (int j = 0; j < 8; ++j) o8[j] = acc[i][j] + bv[j];
        float4* cp = (float4*)&C[(size_t)(m0 + tm * 8 + i) * N + n0 + tn * 8];
        cp[0] = *(float4*)&o8[0];
        cp[1] = *(float4*)&o8[4];
    }
}

// ---------------------------------------------------------------------------
extern "C" void kernel_launch(void* const* d_in, const int* in_sizes, int n_in,
                              void* d_out, int out_size, void* d_ws, size_t ws_size,
                              hipStream_t stream)
{
    const float* x      = (const float*)d_in[0];
    const float* memory = (const float*)d_in[1];
    const float* Wq     = (const float*)d_in[2];
    const float* bq     = (const float*)d_in[3];
    const float* Wk     = (const float*)d_in[4];
    const float* bk     = (const float*)d_in[5];
    const float* Wo     = (const float*)d_in[6];
    const float* bo     = (const float*)d_in[7];
    float* out = (float*)d_out;

    char* ws = (char*)d_ws;
    ushort* qH   = (ushort*)(ws);                         //  8.39 MB
    ushort* qL   = (ushort*)(ws + (size_t) 8388608);      //  8.39 MB
    ushort* keyH = (ushort*)(ws + (size_t)16777216);      //  8.39 MB
    ushort* keyL = (ushort*)(ws + (size_t)25165824);      //  8.39 MB
    float*  att  = (float*) (ws + (size_t)33554432);      // 16.78 MB

    keys_kernel<<<16384, 256, 0, stream>>>(memory, Wk, bk, keyH, keyL);
    gemm_bias_bf16out_kernel<<<dim3(8, 32), 256, 0, stream>>>(x, Wq, bq, qH, qL, 4096, 1024, 1024);
    score_topk_blend_kernel<<<dim3(64, 16, 2), 256, 0, stream>>>(qH, qL, keyH, keyL, memory, att);
    gemm_bias_kernel<<<dim3(8, 32), 256, 0, stream>>>(att, Wo, bo, out, 4096, 1024, 1024);
}

// Round 23
// 1108.153 us; speedup vs baseline: 1.1950x; 1.1950x over previous
//
#include <hip/hip_runtime.h>
#include <math.h>

// ---------------------------------------------------------------------------
// B=2, S=2048, QW=1024, H=16, M=4096, D=64, K=32, OW=1024
// FINAL (best-known = round 19, 1108.7us): split-bf16 MFMA scores + bitonic
// init + serial wave merge + T14 async staging; LDS-staged keys; q fragments
// direct-from-global once.
// Session ledger: r15 occupancy x2 null; r16 crossbar diet null; r17 T14
// WIN (-110us); r18 block-coarsen -; r20 append-buffer -; r21 reg-keys -;
// r22 reg-keys+reorder - (VGPR/occupancy conflict). Residual ~830us is the
// serial top-k chain structure; no resource counter saturated, all
// restructurings regress => practical plateau.
// Numerics: exact-f32-equivalent scores (validated r1-r4), boundary-blend
// over ranks 32..35 (validated r6), absmax stable at 0.171875.
// ---------------------------------------------------------------------------

#define EPS1f 6e-5f
#define EPS2f 2e-4f
#define PADD 72            // key-LDS row stride in shorts (144B, 16B-aligned)

typedef __attribute__((ext_vector_type(8))) short bf16x8;
typedef __attribute__((ext_vector_type(4))) float f32x4;

__device__ __forceinline__ ushort f2bf(float f) {      // RNE float->bf16
    uint u = __float_as_uint(f);
    u += 0x7FFFu + ((u >> 16) & 1u);
    return (ushort)(u >> 16);
}
__device__ __forceinline__ float bf2f(ushort h) {
    return __uint_as_float(((uint)h) << 16);
}

// ascending stable bitonic stage: smaller val first; tie -> larger idx first
__device__ __forceinline__ void bstageA(float& v, int& i, int lane, int j, int k) {
    float pv = __shfl_xor(v, j);
    int   pi = __shfl_xor(i, j);
    bool want_small = (((lane & k) == 0) == ((lane & j) == 0));
    bool me_small   = (v < pv) || (v == pv && i > pi);
    if (want_small != me_small) { v = pv; i = pi; }
}

// ---- keys: kH/kL[h][m][e] = bf16split(sum_d memory[h][m][d]*Wk[h][d][e]+bk)
__global__ __launch_bounds__(256) void keys_kernel(
    const float* __restrict__ mem, const float* __restrict__ Wk,
    const float* __restrict__ bk, ushort* __restrict__ kH,
    ushort* __restrict__ kL)
{
    int o = blockIdx.x * 256 + threadIdx.x;   // h*2^18 + m*64 + e
    int e = o & 63;
    int m = (o >> 6) & 4095;
    int h = o >> 18;
    const float* mrow = mem + (size_t)((h << 12) + m) * 64;
    const float* wcol = Wk + (h << 12) + e;   // stride 64 over d
    double acc = (double)bk[(h << 6) + e];
    #pragma unroll
    for (int d = 0; d < 64; ++d) acc += (double)mrow[d] * (double)wcol[d << 6];
    float v = (float)acc;
    ushort hi = f2bf(v);
    kH[o] = hi;
    kL[o] = f2bf(v - bf2f(hi));
}

// ---- q-proj: fp32 128x128x16 GEMM, epilogue emits bf16 hi/lo planes -------
__global__ __launch_bounds__(256) void gemm_bias_bf16out_kernel(
    const float* __restrict__ A, const float* __restrict__ B,
    const float* __restrict__ bias, ushort* __restrict__ qH,
    ushort* __restrict__ qL, int M, int N, int K)
{
    __shared__ float AsT[16][132];
    __shared__ float Bs[16][132];
    int t  = threadIdx.x;
    int m0 = blockIdx.y * 128, n0 = blockIdx.x * 128;
    int tm = t >> 4, tn = t & 15;
    float acc[8][8] = {};
    for (int k0 = 0; k0 < K; k0 += 16) {
        __syncthreads();
        #pragma unroll
        for (int j = 0; j < 8; ++j) {
            int i = t + j * 256;
            int r = i >> 4, c = i & 15;
            AsT[c][r] = A[(size_t)(m0 + r) * K + k0 + c];
        }
        #pragma unroll
        for (int j = 0; j < 8; ++j) {
            int i = t + j * 256;
            int kk = i >> 7, nn = i & 127;
            Bs[kk][nn] = B[(size_t)(k0 + kk) * N + n0 + nn];
        }
        __syncthreads();
        #pragma unroll
        for (int kk = 0; kk < 16; ++kk) {
            float a[8], b[8];
            *(float4*)&a[0] = *(const float4*)&AsT[kk][tm * 8];
            *(float4*)&a[4] = *(const float4*)&AsT[kk][tm * 8 + 4];
            *(float4*)&b[0] = *(const float4*)&Bs[kk][tn * 8];
            *(float4*)&b[4] = *(const float4*)&Bs[kk][tn * 8 + 4];
            #pragma unroll
            for (int i = 0; i < 8; ++i)
                #pragma unroll
                for (int j = 0; j < 8; ++j)
                    acc[i][j] += a[i] * b[j];
        }
    }
    float bv[8];
    *(float4*)&bv[0] = *(const float4*)&bias[n0 + tn * 8];
    *(float4*)&bv[4] = *(const float4*)&bias[n0 + tn * 8 + 4];
    #pragma unroll
    for (int i = 0; i < 8; ++i) {
        uint ph[4], pl[4];
        #pragma unroll
        for (int j = 0; j < 4; ++j) {
            float o0 = acc[i][2 * j]     + bv[2 * j];
            float o1 = acc[i][2 * j + 1] + bv[2 * j + 1];
            ushort h0 = f2bf(o0), h1 = f2bf(o1);
            ushort l0 = f2bf(o0 - bf2f(h0)), l1 = f2bf(o1 - bf2f(h1));
            ph[j] = (uint)h0 | ((uint)h1 << 16);
            pl[j] = (uint)l0 | ((uint)l1 << 16);
        }
        size_t off = (size_t)(m0 + tm * 8 + i) * N + n0 + tn * 8;
        *(uint4*)&qH[off] = make_uint4(ph[0], ph[1], ph[2], ph[3]);
        *(uint4*)&qL[off] = make_uint4(pl[0], pl[1], pl[2], pl[3]);
    }
}

// ---- fused MFMA score + top-35 (bitonic init + serial merge) + blend ------
// Block 256 (4 waves), one (b,h), 32 s-rows, 64 m-chunks of 64.
// MFMA: wave w computes row-tile (w>>1), col-tiles {(w&1)*2, +1}.
// Merge: wave w owns rows w*8..w*8+7; list ascending on lanes 0..34.
// T14 pipeline: loads(i+1) issued before merge(i); LDS write after.
// LDS 27136 B.
__global__ __launch_bounds__(256) void score_topk_blend_kernel(
    const ushort* __restrict__ qHg, const ushort* __restrict__ qLg,
    const ushort* __restrict__ kHg, const ushort* __restrict__ kLg,
    const float* __restrict__ mem, float* __restrict__ att)
{
    __shared__ char smem[27136];
    ushort* khs = (ushort*)smem;                 // [64][72] hi
    ushort* kls = (ushort*)(smem + 9216);        // [64][72] lo
    float*  sc  = (float*)(smem + 18432);        // [32][68] scores
    float*  gf  = (float*)(smem + 18432);        // [32][36] epilogue gates
    int*    gi  = (int*)smem;                    // [32][36] epilogue (in khs)

    int t     = threadIdx.x;
    int stile = blockIdx.x;          // 0..63
    int h     = blockIdx.y;
    int b     = blockIdx.z;
    int bs0   = b * 2048 + stile * 32;
    int lane  = t & 63;
    int w     = t >> 6;

    int fr  = lane & 15;             // fragment row/col
    int fk  = (lane >> 4) * 8;       // fragment k base
    int rt  = w >> 1;                // compute row-tile
    int ct0 = (w & 1) * 2;           // first compute col-tile

    // ---- q fragments directly from global, ONCE (resident in 16 VGPRs) ----
    bf16x8 Ah[2], Al[2];
    {
        size_t qoff = ((size_t)(bs0 + rt * 16 + fr) << 10) + (h << 6);
        const ushort* qh = qHg + qoff;
        const ushort* ql = qLg + qoff;
        #pragma unroll
        for (int k2 = 0; k2 < 2; ++k2) {
            Ah[k2] = *(const bf16x8*)&qh[k2 * 32 + fk];
            Al[k2] = *(const bf16x8*)&ql[k2 * 32 + fk];
        }
    }

    float LV[8]; int LI[8];
    #pragma unroll
    for (int r = 0; r < 8; ++r) {
        LV[r] = (lane < 35) ? -INFINITY : INFINITY;
        LI[r] = 0;
    }
    int rowbase = w * 8;

    const ushort* kHh = kHg + ((size_t)h << 18);
    const ushort* kLh = kLg + ((size_t)h << 18);

    int f0 = t * 8, f1 = (256 + t) * 8;
    int d0 = (f0 >> 6) * PADD + (f0 & 63);
    int d1 = (f1 >> 6) * PADD + (f1 & 63);

    // MFMA for currently-staged chunk -> sc
    auto do_mfma = [&]() {
        #pragma unroll
        for (int j = 0; j < 2; ++j) {
            int mr = (ct0 + j) * 16 + fr;
            bf16x8 Bh[2], Bl[2];
            #pragma unroll
            for (int k2 = 0; k2 < 2; ++k2) {
                Bh[k2] = *(bf16x8*)&khs[mr * PADD + k2 * 32 + fk];
                Bl[k2] = *(bf16x8*)&kls[mr * PADD + k2 * 32 + fk];
            }
            f32x4 a = {0.f, 0.f, 0.f, 0.f};
            #pragma unroll
            for (int k2 = 0; k2 < 2; ++k2) {
                a = __builtin_amdgcn_mfma_f32_16x16x32_bf16(Ah[k2], Bh[k2], a, 0, 0, 0);
                a = __builtin_amdgcn_mfma_f32_16x16x32_bf16(Ah[k2], Bl[k2], a, 0, 0, 0);
                a = __builtin_amdgcn_mfma_f32_16x16x32_bf16(Al[k2], Bh[k2], a, 0, 0, 0);
                a = __builtin_amdgcn_mfma_f32_16x16x32_bf16(Al[k2], Bl[k2], a, 0, 0, 0);
            }
            int col = (ct0 + j) * 16 + fr;
            int rb  = rt * 16 + (lane >> 4) * 4;
            #pragma unroll
            for (int r = 0; r < 4; ++r)
                sc[(rb + r) * 68 + col] = a[r];
        }
    };

    // streaming serial merge of one chunk (r8-validated), cands in regs
    auto do_merge = [&](int m0, float* cand) {
        #pragma unroll
        for (int ri = 0; ri < 8; ++ri) {
            float c = cand[ri];
            float THR = __shfl(LV[ri], 0);
            while (true) {
                unsigned long long mb = __ballot(c > THR);
                if (mb == 0) break;
                int cc = __ffsll(mb) - 1;
                float val = __shfl(c, cc);
                if (lane == cc) c = -INFINITY;
                unsigned long long less = __ballot(LV[ri] < val);
                int p = __popcll(less);
                float nv = __shfl(LV[ri], lane + 1);
                int   ni = __shfl(LI[ri], lane + 1);
                if (lane == p - 1)      { LV[ri] = val; LI[ri] = m0 + cc; }
                else if (lane < p - 1)  { LV[ri] = nv;  LI[ri] = ni;  }
                THR = __shfl(LV[ri], 0);
            }
        }
    };

    // ---- prologue: stage chunk 0, MFMA chunk 0 ----
    {
        uint4 a0 = *(const uint4*)&kHh[f0];
        uint4 a1 = *(const uint4*)&kHh[f1];
        uint4 b0 = *(const uint4*)&kLh[f0];
        uint4 b1 = *(const uint4*)&kLh[f1];
        *(uint4*)&khs[d0] = a0; *(uint4*)&khs[d1] = a1;
        *(uint4*)&kls[d0] = b0; *(uint4*)&kls[d1] = b1;
    }
    __syncthreads();
    do_mfma();

    // ---- T14 pipelined loop: merge(i) overlaps loads(i+1) ----
    for (int chunk = 0; chunk < 63; ++chunk) {
        int m0 = chunk << 6;
        __syncthreads();             // sc(chunk) complete; khs consumed
        // issue next chunk's global loads into registers (early)
        const ushort* gh = kHh + ((size_t)(m0 + 64) << 6);
        const ushort* gl = kLh + ((size_t)(m0 + 64) << 6);
        uint4 a0 = *(const uint4*)&gh[f0];
        uint4 a1 = *(const uint4*)&gh[f1];
        uint4 b0 = *(const uint4*)&gl[f0];
        uint4 b1 = *(const uint4*)&gl[f1];

        // hoisted candidate reads (8 ds_reads pipeline)
        float cand[8];
        #pragma unroll
        for (int ri = 0; ri < 8; ++ri)
            cand[ri] = sc[(rowbase + ri) * 68 + lane];

        if (chunk == 0) {
            // bitonic init: sort 64 candidates, keep top-35 (stable order)
            #pragma unroll
            for (int ri = 0; ri < 8; ++ri) {
                float v = cand[ri];
                int   i = lane;                       // m0 == 0
                #pragma unroll
                for (int k = 2; k <= 64; k <<= 1)
                    #pragma unroll
                    for (int j2 = k >> 1; j2 > 0; j2 >>= 1)
                        bstageA(v, i, lane, j2, k);
                int src = (lane < 35) ? lane + 29 : 0;
                float sv = __shfl(v, src);
                int   si = __shfl(i, src);
                LV[ri] = (lane < 35) ? sv : INFINITY;
                LI[ri] = (lane < 35) ? si : 0;
            }
        } else {
            do_merge(m0, cand);
        }

        // write-late: staged keys -> LDS (loads landed under the merge)
        *(uint4*)&khs[d0] = a0; *(uint4*)&khs[d1] = a1;
        *(uint4*)&kls[d0] = b0; *(uint4*)&kls[d1] = b1;
        __syncthreads();             // writes visible; sc free (cands in regs)
        do_mfma();                   // chunk+1 -> sc
    }

    __syncthreads();                 // sc(63) ready
    {
        float cand[8];
        #pragma unroll
        for (int ri = 0; ri < 8; ++ri)
            cand[ri] = sc[(rowbase + ri) * 68 + lane];
        do_merge(63 << 6, cand);
    }

    __syncthreads();                 // all merges done; khs/sc reusable
    // blend masses + gates (lane l<35 holds rank 35-l; lane 34 = rank 1)
    #pragma unroll
    for (int ri = 0; ri < 8; ++ri) {
        int row = rowbase + ri;
        float v35 = __shfl(LV[ri], 0);
        float v34 = __shfl(LV[ri], 1);
        float v33 = __shfl(LV[ri], 2);
        float s32 = __shfl(LV[ri], 3);
        auto ramp = [](float gap) -> float {
            if (gap <= EPS1f) return 1.f;
            if (gap >= EPS2f) return 0.f;
            return (EPS2f - gap) / (EPS2f - EPS1f);
        };
        float u33 = ramp(s32 - v33), u34 = ramp(s32 - v34), u35 = ramp(s32 - v35);
        float inv = 1.f / (1.f + u33 + u34 + u35);
        float mass = (lane >= 4) ? 1.f
                   : (lane == 3) ? inv
                   : (lane == 2) ? u33 * inv
                   : (lane == 1) ? u34 * inv
                                 : u35 * inv;
        if (lane < 35) {
            gf[row * 36 + lane] = mass / (1.f + expf(-LV[ri]));
            gi[row * 36 + lane] = LI[ri];
        }
    }
    __syncthreads();

    // gather: wave w rows w*8..+7, lane = d
    for (int ri = 0; ri < 8; ++ri) {
        int row = rowbase + ri;
        float acc = 0.f;
        #pragma unroll 7
        for (int j = 0; j < 35; ++j) {
            float g  = gf[row * 36 + j];
            int  idx = gi[row * 36 + j];
            acc += g * mem[((size_t)((h << 12) + idx) << 6) + lane];
        }
        att[(size_t)(bs0 + row) * 1024 + (h << 6) + lane] = acc;
    }
}

// ---- out-proj: fp32 GEMM + bias -------------------------------------------
__global__ __launch_bounds__(256) void gemm_bias_kernel(
    const float* __restrict__ A, const float* __restrict__ B,
    const float* __restrict__ bias, float* __restrict__ C,
    int M, int N, int K)
{
    __shared__ float AsT[16][132];
    __shared__ float Bs[16][132];
    int t  = threadIdx.x;
    int m0 = blockIdx.y * 128, n0 = blockIdx.x * 128;
    int tm = t >> 4, tn = t & 15;
    float acc[8][8] = {};
    for (int k0 = 0; k0 < K; k0 += 16) {
        __syncthreads();
        #pragma unroll
        for (int j = 0; j < 8; ++j) {
            int i = t + j * 256;
            int r = i >> 4, c = i & 15;
            AsT[c][r] = A[(size_t)(m0 + r) * K + k0 + c];
        }
        #pragma unroll
        for (int j = 0; j < 8; ++j) {
            int i = t + j * 256;
            int kk = i >> 7, nn = i & 127;
            Bs[kk][nn] = B[(size_t)(k0 + kk) * N + n0 + nn];
        }
        __syncthreads();
        #pragma unroll
        for (int kk = 0; kk < 16; ++kk) {
            float a[8], b[8];
            *(float4*)&a[0] = *(const float4*)&AsT[kk][tm * 8];
            *(float4*)&a[4] = *(const float4*)&AsT[kk][tm * 8 + 4];
            *(float4*)&b[0] = *(const float4*)&Bs[kk][tn * 8];
            *(float4*)&b[4] = *(const float4*)&Bs[kk][tn * 8 + 4];
            #pragma unroll
            for (int i = 0; i < 8; ++i)
                #pragma unroll
                for (int j = 0; j < 8; ++j)
                    acc[i][j] += a[i] * b[j];
        }
    }
    float bv[8];
    *(float4*)&bv[0] = *(const float4*)&bias[n0 + tn * 8];
    *(float4*)&bv[4] = *(const float4*)&bias[n0 + tn * 8 + 4];
    #pragma unroll
    for (int i = 0; i < 8; ++i) {
        float o8[8];
        #pragma unroll
        for (int j = 0; j < 8; ++j) o8[j] = acc[i][j] + bv[j];
        float4* cp = (float4*)&C[(size_t)(m0 + tm * 8 + i) * N + n0 + tn * 8];
        cp[0] = *(float4*)&o8[0];
        cp[1] = *(float4*)&o8[4];
    }
}

// ---------------------------------------------------------------------------
extern "C" void kernel_launch(void* const* d_in, const int* in_sizes, int n_in,
                              void* d_out, int out_size, void* d_ws, size_t ws_size,
                              hipStream_t stream)
{
    const float* x      = (const float*)d_in[0];
    const float* memory = (const float*)d_in[1];
    const float* Wq     = (const float*)d_in[2];
    const float* bq     = (const float*)d_in[3];
    const float* Wk     = (const float*)d_in[4];
    const float* bk     = (const float*)d_in[5];
    const float* Wo     = (const float*)d_in[6];
    const float* bo     = (const float*)d_in[7];
    float* out = (float*)d_out;

    char* ws = (char*)d_ws;
    ushort* qH   = (ushort*)(ws);                         //  8.39 MB
    ushort* qL   = (ushort*)(ws + (size_t) 8388608);      //  8.39 MB
    ushort* keyH = (ushort*)(ws + (size_t)16777216);      //  8.39 MB
    ushort* keyL = (ushort*)(ws + (size_t)25165824);      //  8.39 MB
    float*  att  = (float*) (ws + (size_t)33554432);      // 16.78 MB

    keys_kernel<<<16384, 256, 0, stream>>>(memory, Wk, bk, keyH, keyL);
    gemm_bias_bf16out_kernel<<<dim3(8, 32), 256, 0, stream>>>(x, Wq, bq, qH, qL, 4096, 1024, 1024);
    score_topk_blend_kernel<<<dim3(64, 16, 2), 256, 0, stream>>>(qH, qL, keyH, keyL, memory, att);
    gemm_bias_kernel<<<dim3(8, 32), 256, 0, stream>>>(att, Wo, bo, out, 4096, 1024, 1024);
}